// Round 8
// baseline (532.365 us; speedup 1.0000x reference)
//
#include <hip/hip_runtime.h>
#include <math.h>

// Problem constants (fixed by reference): B=64, N=512, D=64, H=4, C=64, L=3
// Workspace layout (floats), ws >= 256 MB:
//   xbuf [0 .. 2097152)         : layer activations x (8 MB)
//   hT   [2097152 .. 10485760)  : h scratch, NEW layout [b][head*64+c][512] (32 MB)
// History: R15/R21 = 266. Mega arc DEAD (~45us/grid-barrier). R20/R21 agg
// micro-fixes NEUTRAL. R22 fuse lin+prep = 282 but gave counters. R23
// wave-independent lin = 237.2 (prediction matched; latency/occupancy theory
// confirmed: 1 wave/SIMD + per-tile syncs was the cost).
// R24 (this): the whole per-layer chain is b-LOCAL -> single layer_kernel,
// grid 64 (one block per b), 1024 thr = 16 waves = 4 waves/SIMD (4x R23):
//   - lin: R23 per-wave body verbatim (wave = (head, quarter), 8 tiles);
//     W staged once for all heads (72KB LDS), frags read per-tile from LDS
//     (keeps VGPR <= 128); hT relaid [b][head*64+c][512] -> L2/L1-hot
//   - prep x4 heads in parallel (verbatim sort per 256-thr group, tl256=t&255);
//     E1/E2/rank/aZ/bZ/k stay in LDS (global meta round-trip DELETED)
//   - agg: 16 chunks x 4 ch; wave (head,chslot) fills+scans one table (R21
//     per-wave code); query sums heads 0..3 in R21 order
//   - LDS peak ~136KB (1 block/CU by design); launch_bounds(1024,4)
//   - dispatches 10 -> 4 (3x layer + readout)
// fp32 op order per output element preserved -> absmax should stay 7.629e-06.
// Decision rule: >=237 -> revert to R23.

using short8  = __attribute__((ext_vector_type(8))) short;
using floatx4 = __attribute__((ext_vector_type(4))) float;

__device__ inline unsigned short f2bf(float f) {
    union { float f; unsigned u; } v; v.f = f;
    unsigned u = v.u + 0x7FFFu + ((v.u >> 16) & 1u);   // round-to-nearest-even
    return (unsigned short)(u >> 16);
}
__device__ inline float bf2f(unsigned short s) {
    union { float f; unsigned u; } v; v.u = ((unsigned)s) << 16;
    return v.f;
}

// 8 floats (two float4) -> split-bf16 hi/lo short8 fragments, in registers.
__device__ inline void cvt8(const float4 a, const float4 b, short8& hi, short8& lo) {
    float f[8] = {a.x, a.y, a.z, a.w, b.x, b.y, b.z, b.w};
    short8 H, L;
#pragma unroll
    for (int i = 0; i < 8; ++i) {
        unsigned short h = f2bf(f[i]);
        H[i] = (short)h;
        L[i] = (short)f2bf(f[i] - bf2f(h));
    }
    hi = H; lo = L;
}

// ---------------------------------------------------------------------------
// layer_kernel: lin + prep(x4 heads) + agg, one block per b, 1024 threads.
// ---------------------------------------------------------------------------
__global__ __launch_bounds__(1024, 4) void layer_kernel(
        const float* __restrict__ x,
        const float* __restrict__ W,
        const float* __restrict__ att_src,
        const float* __restrict__ att_dst,
        const float* __restrict__ bias,
        float* __restrict__ hT,
        float* __restrict__ xout) {
    // Multi-use region: phase0/1 = WH/WL (72KB); prep = sidx/z1/z2; agg = A1/A2.
    __shared__ __align__(16) unsigned char uni[73728];
    __shared__ float sA[4][512], dA[4][512];           // s/d dots; sA sorted in place
    __shared__ float E1s[4][512], E2s[4][512];
    __shared__ int   rnks[4][512];
    __shared__ float aZs[4][512], bZs[4][512];
    __shared__ int   kks[4][512];
    __shared__ float tots[4][4];
    __shared__ float wred[4][8];

    const int t     = threadIdx.x;
    const int b     = blockIdx.x;
    const int tg    = t >> 8;        // head 0..3
    const int tl256 = t & 255;       // index within head group
    const int lane  = t & 63;
    const int wq    = (t >> 6) & 3;  // wave within head group
    const int c0    = tg * 64;

    unsigned short* WH = (unsigned short*)uni;          // [256*72]
    unsigned short* WL = WH + 256 * 72;

    // ---- Phase 0: stage + split-convert ALL 256 W rows (once) ----
#pragma unroll
    for (int q = 0; q < 4; ++q) {
        int f = q * 1024 + t;
        int wrow = f >> 4, d4 = f & 15;
        float4 v = *(const float4*)(W + (size_t)wrow * 64 + d4 * 4);
        unsigned short h0 = f2bf(v.x), h1 = f2bf(v.y), h2 = f2bf(v.z), h3 = f2bf(v.w);
        ushort4 hi = make_ushort4(h0, h1, h2, h3);
        ushort4 lo = make_ushort4(f2bf(v.x - bf2f(h0)), f2bf(v.y - bf2f(h1)),
                                  f2bf(v.z - bf2f(h2)), f2bf(v.w - bf2f(h3)));
        *(ushort4*)&WH[wrow * 72 + d4 * 4] = hi;
        *(ushort4*)&WL[wrow * 72 + d4 * 4] = lo;
    }
    __syncthreads();

    const int mrow = lane & 15, quad = lane >> 4;
    float as_g[4], ad_g[4];
#pragma unroll
    for (int g = 0; g < 4; ++g) {
        as_g[g] = att_src[c0 + g * 16 + mrow];
        ad_g[g] = att_dst[c0 + g * 16 + mrow];
    }

    // ---- lin: wave-independent tiles tl = wq, wq+4, ..., wq+28 (R23 body) ----
    float* hTb = hT + (size_t)b * 131072;   // [head*64+c][512]
    const float* xbase = x + (size_t)(b * 512 + mrow) * 64 + quad * 8;
    float4 nxa = *(const float4*)(xbase + (size_t)wq * 1024);
    float4 nxb = *(const float4*)(xbase + (size_t)wq * 1024 + 4);
    float4 nxc = *(const float4*)(xbase + (size_t)wq * 1024 + 32);
    float4 nxd = *(const float4*)(xbase + (size_t)wq * 1024 + 36);

#pragma unroll 1
    for (int tl = wq; tl < 32; tl += 4) {
        float4 xa = nxa, xb = nxb, xc = nxc, xd = nxd;
        if (tl + 4 < 32) {
            const float* nb = xbase + (size_t)(tl + 4) * 1024;
            nxa = *(const float4*)(nb);
            nxb = *(const float4*)(nb + 4);
            nxc = *(const float4*)(nb + 32);
            nxd = *(const float4*)(nb + 36);
        }
        short8 ah0, al0, ah1, al1;
        cvt8(xa, xb, ah0, al0);
        cvt8(xc, xd, ah1, al1);

        floatx4 acc[4];
#pragma unroll
        for (int g = 0; g < 4; ++g) {
            const int wr = (c0 + g * 16 + mrow) * 72;
            short8 bh0 = *(const short8*)&WH[wr + quad * 8];
            short8 bh1 = *(const short8*)&WH[wr + 32 + quad * 8];
            short8 bl0 = *(const short8*)&WL[wr + quad * 8];
            short8 bl1 = *(const short8*)&WL[wr + 32 + quad * 8];
            floatx4 a = {0.f, 0.f, 0.f, 0.f};
            a = __builtin_amdgcn_mfma_f32_16x16x32_bf16(ah0, bh0, a, 0, 0, 0);
            a = __builtin_amdgcn_mfma_f32_16x16x32_bf16(ah1, bh1, a, 0, 0, 0);
            a = __builtin_amdgcn_mfma_f32_16x16x32_bf16(ah0, bl0, a, 0, 0, 0);
            a = __builtin_amdgcn_mfma_f32_16x16x32_bf16(ah1, bl1, a, 0, 0, 0);
            a = __builtin_amdgcn_mfma_f32_16x16x32_bf16(al0, bh0, a, 0, 0, 0);
            a = __builtin_amdgcn_mfma_f32_16x16x32_bf16(al1, bh1, a, 0, 0, 0);
            acc[g] = a;
        }

#pragma unroll
        for (int g = 0; g < 4; ++g) {
            *(float4*)&hTb[(size_t)(c0 + g * 16 + mrow) * 512 + tl * 16 + quad * 4] =
                make_float4(acc[g][0], acc[g][1], acc[g][2], acc[g][3]);
        }

        float ps[4], pd[4];
#pragma unroll
        for (int reg = 0; reg < 4; ++reg) {
            ps[reg] = acc[0][reg] * as_g[0] + acc[1][reg] * as_g[1]
                    + acc[2][reg] * as_g[2] + acc[3][reg] * as_g[3];
            pd[reg] = acc[0][reg] * ad_g[0] + acc[1][reg] * ad_g[1]
                    + acc[2][reg] * ad_g[2] + acc[3][reg] * ad_g[3];
        }
#pragma unroll
        for (int m = 1; m <= 8; m <<= 1) {
#pragma unroll
            for (int reg = 0; reg < 4; ++reg) {
                ps[reg] += __shfl_xor(ps[reg], m, 64);
                pd[reg] += __shfl_xor(pd[reg], m, 64);
            }
        }
        if (mrow < 4) {
            sA[tg][tl * 16 + quad * 4 + mrow] = ps[mrow];
            dA[tg][tl * 16 + quad * 4 + mrow] = pd[mrow];
        }
    }
    __syncthreads();

    // ======================= prep (verbatim, x4 heads in parallel) ==========
    int*   sidx = (int*)uni;                        // [4][512]
    float* z1   = (float*)(uni + 8192);             // [4][513]
    float* z2   = (float*)(uni + 8192 + 8208);      // [4][513]
    const int wid = wq;

    float dreg[2];
    for (int rr = 0; rr < 2; ++rr) dreg[rr] = dA[tg][tl256 + rr * 256];

    float v0 = sA[tg][2 * tl256], v1 = sA[tg][2 * tl256 + 1];
    int id0 = 2 * tl256, id1 = 2 * tl256 + 1;
    for (int k = 2; k <= 512; k <<= 1) {
        for (int j = k >> 1; j >= 1; j >>= 1) {
            bool asc = ((tl256 & (k >> 1)) == 0);
            if (j == 1) {
                bool sw = asc ? (v0 > v1) : (v0 < v1);
                if (sw) { float tv = v0; v0 = v1; v1 = tv; int ti = id0; id0 = id1; id1 = ti; }
            } else if (j <= 64) {
                int m = j >> 1;
                float w0 = __shfl_xor(v0, m, 64);
                int  wi0 = __shfl_xor(id0, m, 64);
                float w1 = __shfl_xor(v1, m, 64);
                int  wi1 = __shfl_xor(id1, m, 64);
                bool low = ((tl256 & m) == 0);
                bool wantmin = (low == asc);
                if (wantmin ? (w0 < v0) : (w0 > v0)) { v0 = w0; id0 = wi0; }
                if (wantmin ? (w1 < v1) : (w1 > v1)) { v1 = w1; id1 = wi1; }
            } else {
                int m = j >> 1;
                sA[tg][2 * tl256] = v0; sA[tg][2 * tl256 + 1] = v1;
                sidx[tg * 512 + 2 * tl256] = id0; sidx[tg * 512 + 2 * tl256 + 1] = id1;
                __syncthreads();
                int tp = tl256 ^ m;
                float w0 = sA[tg][2 * tp], w1 = sA[tg][2 * tp + 1];
                int wi0 = sidx[tg * 512 + 2 * tp], wi1 = sidx[tg * 512 + 2 * tp + 1];
                bool low = ((tl256 & m) == 0);
                bool wantmin = (low == asc);
                if (wantmin ? (w0 < v0) : (w0 > v0)) { v0 = w0; id0 = wi0; }
                if (wantmin ? (w1 < v1) : (w1 > v1)) { v1 = w1; id1 = wi1; }
                __syncthreads();
            }
        }
    }

    sA[tg][2 * tl256] = v0; sA[tg][2 * tl256 + 1] = v1;
    __syncthreads();
    const float M = sA[tg][511];
    float e1_0 = __expf(v0 - M), e1_1 = __expf(v1 - M);
    float e2_0 = __expf(0.2f * (v0 - M)), e2_1 = __expf(0.2f * (v1 - M));
    {   // scatter by original id into LDS (permutation -> race-free)
        E1s[tg][id0] = e1_0;  E1s[tg][id1] = e1_1;
        E2s[tg][id0] = e2_0;  E2s[tg][id1] = e2_1;
        rnks[tg][id0] = 2 * tl256;  rnks[tg][id1] = 2 * tl256 + 1;
    }

    float S1 = e1_0 + e1_1, S2 = e2_0 + e2_1;
    float i1 = S1, i2 = S2;
    for (int off = 1; off < 64; off <<= 1) {
        float u1 = __shfl_up(i1, off, 64);
        float u2 = __shfl_up(i2, off, 64);
        if (lane >= off) { i1 += u1; i2 += u2; }
    }
    if (lane == 63) { wred[tg][wid] = i1; wred[tg][4 + wid] = i2; }
    __syncthreads();
    float off1 = 0.f, off2 = 0.f;
    for (int w = 0; w < wid; ++w) { off1 += wred[tg][w]; off2 += wred[tg][4 + w]; }
    const float T1 = wred[tg][0] + wred[tg][1] + wred[tg][2] + wred[tg][3];
    const float T2 = wred[tg][4] + wred[tg][5] + wred[tg][6] + wred[tg][7];
    float pre1 = off1 + i1 - S1;
    float pre2 = off2 + i2 - S2;
    z1[tg * 513 + 2 * tl256] = T1 - pre1;
    z1[tg * 513 + 2 * tl256 + 1] = T1 - pre1 - e1_0;
    z2[tg * 513 + 2 * tl256] = pre2;
    z2[tg * 513 + 2 * tl256 + 1] = pre2 + e2_0;
    if (tl256 == 0) { z1[tg * 513 + 512] = 0.f; z2[tg * 513 + 512] = T2; }
    __syncthreads();

    for (int rr = 0; rr < 2; ++rr) {
        int i = tl256 + rr * 256;
        float d = dreg[rr];
        int lo = 0, hi = 512;
        while (lo < hi) {
            int mid = (lo + hi) >> 1;
            if (d + sA[tg][mid] >= 0.f) hi = mid; else lo = mid + 1;
        }
        int k = lo;
        float g = d + M;
        float G = (g >= 0.f) ? g : 0.2f * g;
        float al = __expf(g - G);
        float be = __expf(0.2f * g - G);
        float Z = al * z1[tg * 513 + k] + be * z2[tg * 513 + k];
        float inv = 1.0f / Z;
        aZs[tg][i] = al * inv;
        bZs[tg][i] = be * inv;
        kks[tg][i] = k;
    }
    __syncthreads();   // prep outputs ready; uni scratch (sidx/z1/z2) now free

    // ======================= agg (R21 per-wave fill+scan, 16 chunks) ========
    float* A1 = (float*)uni;                // [4][4][512] = 32 KB
    float* A2 = (float*)(uni + 32768);      // [4][4][512] = 32 KB
    const int chp = t & 3, iq = t >> 2;     // query mapping

#pragma unroll 1
    for (int chunk = 0; chunk < 16; ++chunk) {
        // ---- fill + scan: wave (tg, wq) owns channel ch of head tg ----
        {
            const int ch = chunk * 4 + wq;
            float* T1p = A1 + (tg * 4 + wq) * 512;
            float* T2p = A2 + (tg * 4 + wq) * 512;
            const float* hTc = hTb + (size_t)(c0 + ch) * 512;
#pragma unroll
            for (int it = 0; it < 8; ++it) {
                int j = it * 64 + lane;
                int rk = rnks[tg][j];
                float e1 = E1s[tg][j];
                float e2 = E2s[tg][j];
                float hv = hTc[j];
                int pk = ((rk & 7) << 6) | (rk >> 3);
                T1p[pk] = e1 * hv;
                T2p[pk] = e2 * hv;
            }
            float v1s[8], v2s[8];
#pragma unroll
            for (int i = 0; i < 8; ++i) {
                v1s[i] = T1p[i * 64 + lane];
                v2s[i] = T2p[i * 64 + lane];
            }
            float s1 = 0.f, s2 = 0.f;
#pragma unroll
            for (int i = 0; i < 8; ++i) { s1 += v1s[i]; s2 += v2s[i]; }
            float suf = s1;
#pragma unroll
            for (int off = 1; off < 64; off <<= 1) {
                float u = __shfl_down(suf, off, 64);
                if (lane + off < 64) suf += u;
            }
            float run = suf - s1;                 // exclusive suffix
            float pre = s2;
#pragma unroll
            for (int off = 1; off < 64; off <<= 1) {
                float u = __shfl_up(pre, off, 64);
                if (lane >= off) pre += u;
            }
            float run2 = pre - s2;                // exclusive prefix
            if (lane == 63) tots[tg][wq] = pre;   // channel total
#pragma unroll
            for (int i = 7; i >= 0; --i) { run += v1s[i]; v1s[i] = run; }        // incl suffix
#pragma unroll
            for (int i = 0; i < 8; ++i) { float tv = v2s[i]; v2s[i] = run2; run2 += tv; } // excl prefix
#pragma unroll
            for (int i = 0; i < 8; ++i) {
                T1p[i * 64 + lane] = v1s[i];
                T2p[i * 64 + lane] = v2s[i];
            }
        }
        __syncthreads();

        // ---- query: thread handles (i = iq, iq+256; channel chunk*4+chp) ----
        {
            const int cq = chunk * 4 + chp;
            const float bv = bias[cq];
#pragma unroll
            for (int rr = 0; rr < 2; ++rr) {
                int i = iq + rr * 256;
                float a = 0.f;
#pragma unroll
                for (int h = 0; h < 4; ++h) {
                    float aZ = aZs[h][i];
                    float bZ = bZs[h][i];
                    int k = kks[h][i];
                    if (k < 512) {
                        int pk = ((k & 7) << 6) | (k >> 3);
                        a += aZ * A1[(h * 4 + chp) * 512 + pk]
                           + bZ * A2[(h * 4 + chp) * 512 + pk];
                    } else {
                        a += bZ * tots[h][chp];
                    }
                }
                xout[(size_t)(b * 512 + i) * 64 + cq] = fmaxf(0.25f * a + bv, 0.f);
            }
        }
        __syncthreads();   // queries done before next chunk overwrites tables
    }
}

// ---------------------------------------------------------------------------
// Kernel D: readout (unchanged)
// ---------------------------------------------------------------------------
__global__ __launch_bounds__(256) void readout_kernel(const float* __restrict__ x,
                                                      const float* __restrict__ rw,
                                                      const float* __restrict__ rb,
                                                      float* __restrict__ out) {
    __shared__ float red[4][64];
    __shared__ float pooled[64];
    int b = blockIdx.x, t = threadIdx.x;
    int c = t & 63, q = t >> 6;
    float acc = 0.f;
    for (int n = q; n < 512; n += 4) acc += x[((size_t)b * 512 + n) * 64 + c];
    red[q][c] = acc;
    __syncthreads();
    if (t < 64) pooled[t] = (red[0][t] + red[1][t] + red[2][t] + red[3][t]) * (1.0f / 512.0f);
    __syncthreads();
    if (t < 64) {
        float a = rb[t];
        for (int cc = 0; cc < 64; ++cc) a += pooled[cc] * rw[t * 64 + cc];
        out[b * 64 + t] = a;
    }
}

extern "C" void kernel_launch(void* const* d_in, const int* in_sizes, int n_in,
                              void* d_out, int out_size, void* d_ws, size_t ws_size,
                              hipStream_t stream) {
    const float* emb       = (const float*)d_in[0];
    const float* lin_w     = (const float*)d_in[1];
    const float* att_src   = (const float*)d_in[2];
    const float* att_dst   = (const float*)d_in[3];
    const float* conv_b    = (const float*)d_in[4];
    const float* readout_w = (const float*)d_in[5];
    const float* readout_b = (const float*)d_in[6];
    float* out = (float*)d_out;

    float* ws   = (float*)d_ws;
    float* xbuf = ws;                    // 8 MB
    float* hT   = ws + 2097152;          // 32 MB, [b][head*64+c][512]

    for (int l = 0; l < 3; ++l) {
        const float* xin = (l == 0) ? emb : xbuf;
        layer_kernel<<<64, 1024, 0, stream>>>(xin, lin_w + (size_t)l * 16384,
                                              att_src + l * 256, att_dst + l * 256,
                                              conv_b + l * 64, hT, xbuf);
    }
    readout_kernel<<<64, 256, 0, stream>>>(xbuf, readout_w, readout_b, out);
}

// Round 9
// 240.397 us; speedup vs baseline: 2.2145x; 2.2145x over previous
//
#include <hip/hip_runtime.h>
#include <math.h>

// Problem constants (fixed by reference): B=64, N=512, D=64, H=4, C=64, L=3
// Workspace layout (floats), ws >= 256 MB:
//   xbuf [0 .. 2097152)         : layer activations x (8 MB)
//   hT   [2097152 .. 10485760)  : h TRANSPOSED [head][c][b*512+n] (32 MB)
//   meta [10485760 .. 11534336) : prep metadata (4 MB)
// History: R15/R21 = 266. Mega arc DEAD. R23 (wave-independent fused
// lin+prep, grid 256) = 237.2 — best. R24 b-local full fusion (grid 64)
// = 532: only 64/256 CUs occupied + 16-wave serial chain -> REVERTED.
// Lesson: count blocks-vs-CUs before counting latency.
// R25 (this): R23 verbatim + ONE change: agg goes 1 channel/block
// (grid 4096, LDS 16KB+ vs 33KB) -> blocks/CU 5 -> 8 (wave-slot limited),
// half the serial fill/scan/query per block. Same total work, same access
// patterns, same per-output fp32 op order -> absmax must stay 7.629e-06.
// Decision rule: >=237 -> revert agg to R21 2-ch variant.

using short8  = __attribute__((ext_vector_type(8))) short;
using floatx4 = __attribute__((ext_vector_type(4))) float;

__device__ inline unsigned short f2bf(float f) {
    union { float f; unsigned u; } v; v.f = f;
    unsigned u = v.u + 0x7FFFu + ((v.u >> 16) & 1u);   // round-to-nearest-even
    return (unsigned short)(u >> 16);
}
__device__ inline float bf2f(unsigned short s) {
    union { float f; unsigned u; } v; v.u = ((unsigned)s) << 16;
    return v.f;
}

// 8 floats (two float4) -> split-bf16 hi/lo short8 fragments, in registers.
__device__ inline void cvt8(const float4 a, const float4 b, short8& hi, short8& lo) {
    float f[8] = {a.x, a.y, a.z, a.w, b.x, b.y, b.z, b.w};
    short8 H, L;
#pragma unroll
    for (int i = 0; i < 8; ++i) {
        unsigned short h = f2bf(f[i]);
        H[i] = (short)h;
        L[i] = (short)f2bf(f[i] - bf2f(h));
    }
    hi = H; lo = L;
}

// ---------------------------------------------------------------------------
// Kernel A+B1 fused: linprep v2 (R23, UNCHANGED) — wave-independent lin +
// verbatim prep. grid 256 = (b,head), 256 threads.
// ---------------------------------------------------------------------------
__global__ __launch_bounds__(256) void linprep_kernel(const float* __restrict__ x,
                                                      const float* __restrict__ W,
                                                      const float* __restrict__ att_src,
                                                      const float* __restrict__ att_dst,
                                                      float* __restrict__ hT,
                                                      int* __restrict__ g_rank,
                                                      float* __restrict__ g_E1,
                                                      float* __restrict__ g_E2,
                                                      float* __restrict__ g_aZ,
                                                      float* __restrict__ g_bZ,
                                                      int* __restrict__ g_k) {
    __shared__ unsigned short WH[64 * 72], WL[64 * 72];
    __shared__ float sA[512], dA[512];      // s/d dots (then sA sorted in place)
    __shared__ int   s_idxE[512];
    __shared__ float z1suf[513], z2pre[513];
    __shared__ float wred[8];

    const int t  = threadIdx.x;
    const int bh = blockIdx.x;            // b*4 + head (matches meta layout)
    const int b  = bh >> 2;
    const int ct = bh & 3;                // head
    const int c0 = ct * 64;

    // ---- W staging + convert, ONCE per block ----
#pragma unroll
    for (int q = 0; q < 4; ++q) {
        int f = q * 256 + t;
        int wrow = f >> 4, d4 = f & 15;
        float4 v = *(const float4*)(W + (size_t)(c0 + wrow) * 64 + d4 * 4);
        unsigned short h0 = f2bf(v.x), h1 = f2bf(v.y), h2 = f2bf(v.z), h3 = f2bf(v.w);
        ushort4 hi = make_ushort4(h0, h1, h2, h3);
        ushort4 lo = make_ushort4(f2bf(v.x - bf2f(h0)), f2bf(v.y - bf2f(h1)),
                                  f2bf(v.z - bf2f(h2)), f2bf(v.w - bf2f(h3)));
        *(ushort4*)&WH[wrow * 72 + d4 * 4] = hi;
        *(ushort4*)&WL[wrow * 72 + d4 * 4] = lo;
    }
    __syncthreads();

    const int lane = t & 63, wv = t >> 6;
    const int mrow = lane & 15, quad = lane >> 4;

    // ---- per-wave W fragments for ALL 4 channel groups ----
    short8 bhf[4][2], blf[4][2];
#pragma unroll
    for (int g = 0; g < 4; ++g)
#pragma unroll
        for (int kk = 0; kk < 2; ++kk) {
            int ko = kk * 32 + quad * 8;
            bhf[g][kk] = *(const short8*)&WH[(g * 16 + mrow) * 72 + ko];
            blf[g][kk] = *(const short8*)&WL[(g * 16 + mrow) * 72 + ko];
        }
    float as_g[4], ad_g[4];
#pragma unroll
    for (int g = 0; g < 4; ++g) {
        as_g[g] = att_src[c0 + g * 16 + mrow];
        ad_g[g] = att_dst[c0 + g * 16 + mrow];
    }

    // ---- wave-independent tile loop: wave wv owns tiles wv, wv+4, ..., wv+28
    const float* xbase = x + (size_t)(b * 512 + mrow) * 64 + quad * 8;
    float4 nxa = *(const float4*)(xbase + (size_t)wv * 1024);
    float4 nxb = *(const float4*)(xbase + (size_t)wv * 1024 + 4);
    float4 nxc = *(const float4*)(xbase + (size_t)wv * 1024 + 32);
    float4 nxd = *(const float4*)(xbase + (size_t)wv * 1024 + 36);

#pragma unroll 1
    for (int tl = wv; tl < 32; tl += 4) {
        float4 xa = nxa, xb = nxb, xc = nxc, xd = nxd;
        if (tl + 4 < 32) {
            const float* nb = xbase + (size_t)(tl + 4) * 1024;
            nxa = *(const float4*)(nb);
            nxb = *(const float4*)(nb + 4);
            nxc = *(const float4*)(nb + 32);
            nxd = *(const float4*)(nb + 36);
        }
        short8 ah0, al0, ah1, al1;
        cvt8(xa, xb, ah0, al0);
        cvt8(xc, xd, ah1, al1);

        floatx4 acc[4];
#pragma unroll
        for (int g = 0; g < 4; ++g) {
            floatx4 a = {0.f, 0.f, 0.f, 0.f};
            a = __builtin_amdgcn_mfma_f32_16x16x32_bf16(ah0, bhf[g][0], a, 0, 0, 0);
            a = __builtin_amdgcn_mfma_f32_16x16x32_bf16(ah1, bhf[g][1], a, 0, 0, 0);
            a = __builtin_amdgcn_mfma_f32_16x16x32_bf16(ah0, blf[g][0], a, 0, 0, 0);
            a = __builtin_amdgcn_mfma_f32_16x16x32_bf16(ah1, blf[g][1], a, 0, 0, 0);
            a = __builtin_amdgcn_mfma_f32_16x16x32_bf16(al0, bhf[g][0], a, 0, 0, 0);
            a = __builtin_amdgcn_mfma_f32_16x16x32_bf16(al1, bhf[g][1], a, 0, 0, 0);
            acc[g] = a;
        }

        const int r0 = b * 512 + tl * 16;
#pragma unroll
        for (int g = 0; g < 4; ++g) {
            *(float4*)&hT[(size_t)(ct * 64 + g * 16 + mrow) * 32768 + r0 + quad * 4] =
                make_float4(acc[g][0], acc[g][1], acc[g][2], acc[g][3]);
        }

        float ps[4], pd[4];
#pragma unroll
        for (int reg = 0; reg < 4; ++reg) {
            ps[reg] = acc[0][reg] * as_g[0] + acc[1][reg] * as_g[1]
                    + acc[2][reg] * as_g[2] + acc[3][reg] * as_g[3];
            pd[reg] = acc[0][reg] * ad_g[0] + acc[1][reg] * ad_g[1]
                    + acc[2][reg] * ad_g[2] + acc[3][reg] * ad_g[3];
        }
#pragma unroll
        for (int m = 1; m <= 8; m <<= 1) {
#pragma unroll
            for (int reg = 0; reg < 4; ++reg) {
                ps[reg] += __shfl_xor(ps[reg], m, 64);
                pd[reg] += __shfl_xor(pd[reg], m, 64);
            }
        }
        if (mrow < 4) {
            sA[tl * 16 + quad * 4 + mrow] = ps[mrow];
            dA[tl * 16 + quad * 4 + mrow] = pd[mrow];
        }
    }
    __syncthreads();

    // ======================= prep body (verbatim) ==========================
    const int wid = t >> 6;

    float dreg[2];
    for (int rr = 0; rr < 2; ++rr) dreg[rr] = dA[t + rr * 256];

    float v0 = sA[2 * t], v1 = sA[2 * t + 1];
    int id0 = 2 * t, id1 = 2 * t + 1;
    for (int k = 2; k <= 512; k <<= 1) {
        for (int j = k >> 1; j >= 1; j >>= 1) {
            bool asc = ((t & (k >> 1)) == 0);
            if (j == 1) {
                bool sw = asc ? (v0 > v1) : (v0 < v1);
                if (sw) { float tv = v0; v0 = v1; v1 = tv; int ti = id0; id0 = id1; id1 = ti; }
            } else if (j <= 64) {
                int m = j >> 1;
                float w0 = __shfl_xor(v0, m, 64);
                int  wi0 = __shfl_xor(id0, m, 64);
                float w1 = __shfl_xor(v1, m, 64);
                int  wi1 = __shfl_xor(id1, m, 64);
                bool low = ((t & m) == 0);
                bool wantmin = (low == asc);
                if (wantmin ? (w0 < v0) : (w0 > v0)) { v0 = w0; id0 = wi0; }
                if (wantmin ? (w1 < v1) : (w1 > v1)) { v1 = w1; id1 = wi1; }
            } else {
                int m = j >> 1;
                sA[2 * t] = v0; sA[2 * t + 1] = v1;
                s_idxE[2 * t] = id0; s_idxE[2 * t + 1] = id1;
                __syncthreads();
                int tp = t ^ m;
                float w0 = sA[2 * tp], w1 = sA[2 * tp + 1];
                int wi0 = s_idxE[2 * tp], wi1 = s_idxE[2 * tp + 1];
                bool low = ((t & m) == 0);
                bool wantmin = (low == asc);
                if (wantmin ? (w0 < v0) : (w0 > v0)) { v0 = w0; id0 = wi0; }
                if (wantmin ? (w1 < v1) : (w1 > v1)) { v1 = w1; id1 = wi1; }
                __syncthreads();
            }
        }
    }

    sA[2 * t] = v0; sA[2 * t + 1] = v1;
    __syncthreads();
    const float M = sA[511];
    float e1_0 = __expf(v0 - M), e1_1 = __expf(v1 - M);
    float e2_0 = __expf(0.2f * (v0 - M)), e2_1 = __expf(0.2f * (v1 - M));
    {
        const int base = bh * 512;
        g_E1[base + id0] = e1_0;  g_E1[base + id1] = e1_1;
        g_E2[base + id0] = e2_0;  g_E2[base + id1] = e2_1;
        g_rank[base + id0] = 2 * t;  g_rank[base + id1] = 2 * t + 1;
    }

    float S1 = e1_0 + e1_1, S2 = e2_0 + e2_1;
    float i1 = S1, i2 = S2;
    for (int off = 1; off < 64; off <<= 1) {
        float u1 = __shfl_up(i1, off, 64);
        float u2 = __shfl_up(i2, off, 64);
        if (lane >= off) { i1 += u1; i2 += u2; }
    }
    if (lane == 63) { wred[wid] = i1; wred[4 + wid] = i2; }
    __syncthreads();
    float off1 = 0.f, off2 = 0.f;
    for (int w = 0; w < wid; ++w) { off1 += wred[w]; off2 += wred[4 + w]; }
    const float T1 = wred[0] + wred[1] + wred[2] + wred[3];
    const float T2 = wred[4] + wred[5] + wred[6] + wred[7];
    float pre1 = off1 + i1 - S1;
    float pre2 = off2 + i2 - S2;
    z1suf[2 * t] = T1 - pre1;
    z1suf[2 * t + 1] = T1 - pre1 - e1_0;
    z2pre[2 * t] = pre2;
    z2pre[2 * t + 1] = pre2 + e2_0;
    if (t == 0) { z1suf[512] = 0.f; z2pre[512] = T2; }
    __syncthreads();

    for (int rr = 0; rr < 2; ++rr) {
        int i = t + rr * 256;
        float d = dreg[rr];
        int lo = 0, hi = 512;
        while (lo < hi) {
            int mid = (lo + hi) >> 1;
            if (d + sA[mid] >= 0.f) hi = mid; else lo = mid + 1;
        }
        int k = lo;
        float g = d + M;
        float G = (g >= 0.f) ? g : 0.2f * g;
        float al = __expf(g - G);
        float be = __expf(0.2f * g - G);
        float Z = al * z1suf[k] + be * z2pre[k];
        float inv = 1.0f / Z;
        g_aZ[bh * 512 + i] = al * inv;
        g_bZ[bh * 512 + i] = be * inv;
        g_k[bh * 512 + i]  = k;
    }
}

// ---------------------------------------------------------------------------
// Kernel B2: attn_agg_fin v8 (R25) — ONE channel per block.
// grid = 64 b x 64 ch = 4096 blocks, 256 thr (4 waves = 4 heads).
// LDS 16KB+ -> 8 blocks/CU (wave-slot limited) vs 5 before. Per-block serial
// fill/scan/query work halved. Same math order per output -> bit-identical.
// ---------------------------------------------------------------------------
__global__ __launch_bounds__(256) void attn_agg_fin(const float* __restrict__ hT,
                                                    const int* __restrict__ g_rank,
                                                    const float* __restrict__ g_E1,
                                                    const float* __restrict__ g_E2,
                                                    const float* __restrict__ g_aZ,
                                                    const float* __restrict__ g_bZ,
                                                    const int* __restrict__ g_k,
                                                    const float* __restrict__ bias,
                                                    float* __restrict__ x) {
    const int b  = blockIdx.x & 63;
    const int ch = blockIdx.x >> 6;        // 0..63
    const int t = threadIdx.x;
    const int lane = t & 63, wv = t >> 6;  // wv = head 0..3

    __shared__ float A1[4][512], A2[4][512];
    __shared__ float tots[4];

    // ---- Phase 1: wave wv fills + scans head wv's table for channel ch ----
    {
        const int bh = b * 4 + wv;
        const int base = bh * 512;
        const float* hTc = hT + (size_t)(wv * 64 + ch) * 32768 + (size_t)b * 512;
#pragma unroll
        for (int it = 0; it < 8; ++it) {
            int j = it * 64 + lane;
            int rk = g_rank[base + j];
            float e1 = g_E1[base + j];
            float e2 = g_E2[base + j];
            float hv = hTc[j];
            int pk = ((rk & 7) << 6) | (rk >> 3);
            A1[wv][pk] = e1 * hv;
            A2[wv][pk] = e2 * hv;
        }
        float v1[8], v2[8];
#pragma unroll
        for (int i = 0; i < 8; ++i) {
            v1[i] = A1[wv][i * 64 + lane];
            v2[i] = A2[wv][i * 64 + lane];
        }
        float s1 = 0.f, s2 = 0.f;
#pragma unroll
        for (int i = 0; i < 8; ++i) { s1 += v1[i]; s2 += v2[i]; }
        float suf = s1;
#pragma unroll
        for (int off = 1; off < 64; off <<= 1) {
            float u = __shfl_down(suf, off, 64);
            if (lane + off < 64) suf += u;
        }
        float run = suf - s1;                 // exclusive suffix (seg = lane)
        float pre = s2;
#pragma unroll
        for (int off = 1; off < 64; off <<= 1) {
            float u = __shfl_up(pre, off, 64);
            if (lane >= off) pre += u;
        }
        float run2 = pre - s2;                // exclusive prefix
        if (lane == 63) tots[wv] = pre;       // channel total
#pragma unroll
        for (int i = 7; i >= 0; --i) { run += v1[i]; v1[i] = run; }          // incl suffix
#pragma unroll
        for (int i = 0; i < 8; ++i) { float tv = v2[i]; v2[i] = run2; run2 += tv; } // excl prefix
#pragma unroll
        for (int i = 0; i < 8; ++i) {
            A1[wv][i * 64 + lane] = v1[i];
            A2[wv][i * 64 + lane] = v2[i];
        }
    }
    __syncthreads();

    // ---- Phase 2: queries; thread t handles i = t and t + 256 ----
    const float bv = bias[ch];
#pragma unroll
    for (int rr = 0; rr < 2; ++rr) {
        const int i = t + rr * 256;
        float a = 0.f;
#pragma unroll
        for (int head = 0; head < 4; ++head) {
            const int base = (b * 4 + head) * 512;
            float aZ = g_aZ[base + i];
            float bZ = g_bZ[base + i];
            int k = g_k[base + i];
            if (k < 512) {
                int pk = ((k & 7) << 6) | (k >> 3);
                a += aZ * A1[head][pk] + bZ * A2[head][pk];
            } else {
                a += bZ * tots[head];
            }
        }
        x[(size_t)(b * 512 + i) * 64 + ch] = fmaxf(0.25f * a + bv, 0.f);
    }
}

// ---------------------------------------------------------------------------
// Kernel D: readout (unchanged)
// ---------------------------------------------------------------------------
__global__ __launch_bounds__(256) void readout_kernel(const float* __restrict__ x,
                                                      const float* __restrict__ rw,
                                                      const float* __restrict__ rb,
                                                      float* __restrict__ out) {
    __shared__ float red[4][64];
    __shared__ float pooled[64];
    int b = blockIdx.x, t = threadIdx.x;
    int c = t & 63, q = t >> 6;
    float acc = 0.f;
    for (int n = q; n < 512; n += 4) acc += x[((size_t)b * 512 + n) * 64 + c];
    red[q][c] = acc;
    __syncthreads();
    if (t < 64) pooled[t] = (red[0][t] + red[1][t] + red[2][t] + red[3][t]) * (1.0f / 512.0f);
    __syncthreads();
    if (t < 64) {
        float a = rb[t];
        for (int cc = 0; cc < 64; ++cc) a += pooled[cc] * rw[t * 64 + cc];
        out[b * 64 + t] = a;
    }
}

extern "C" void kernel_launch(void* const* d_in, const int* in_sizes, int n_in,
                              void* d_out, int out_size, void* d_ws, size_t ws_size,
                              hipStream_t stream) {
    const float* emb       = (const float*)d_in[0];
    const float* lin_w     = (const float*)d_in[1];
    const float* att_src   = (const float*)d_in[2];
    const float* att_dst   = (const float*)d_in[3];
    const float* conv_b    = (const float*)d_in[4];
    const float* readout_w = (const float*)d_in[5];
    const float* readout_b = (const float*)d_in[6];
    float* out = (float*)d_out;

    float* ws   = (float*)d_ws;
    float* xbuf = ws;                    // 8 MB
    float* hT   = ws + 2097152;          // 32 MB, [head][c][b*512+n]
    float* meta = ws + 10485760;         // 4 MB

    int*   g_rank = (int*)meta;          // inverse rank (by original id)
    float* g_E1   = meta + 131072;       // indexed by ORIGINAL id
    float* g_E2   = meta + 262144;       // indexed by ORIGINAL id
    float* g_aZ   = meta + 393216;
    float* g_bZ   = meta + 524288;
    int*   g_k    = (int*)(meta + 655360);

    for (int l = 0; l < 3; ++l) {
        const float* xin = (l == 0) ? emb : xbuf;
        linprep_kernel<<<256, 256, 0, stream>>>(xin, lin_w + (size_t)l * 16384,
                                                att_src + l * 256, att_dst + l * 256,
                                                hT, g_rank, g_E1, g_E2, g_aZ, g_bZ, g_k);
        attn_agg_fin<<<4096, 256, 0, stream>>>(hT, g_rank, g_E1, g_E2, g_aZ, g_bZ, g_k,
                                               conv_b + l * 64, xbuf);
    }
    readout_kernel<<<64, 256, 0, stream>>>(xbuf, readout_w, readout_b, out);
}